// Round 1
// baseline (378.862 us; speedup 1.0000x reference)
//
#include <hip/hip_runtime.h>

// SelfAttention: S=4096, EMB=2048, DQ=DV=2048, causal softmax(QK^T/sqrt(DQ))V
// Strategy: bf16 MFMA GEMMs (m97-style 128x128 tile, global_load_lds w16),
// materialized bf16 score matrix with block-causal skip, in-place row softmax,
// K-clamped PV GEMM.

using u16 = unsigned short;
typedef __bf16 bf16x8 __attribute__((ext_vector_type(8)));
typedef float  f32x4  __attribute__((ext_vector_type(4)));
typedef u16    u16x8  __attribute__((ext_vector_type(8)));

__device__ __forceinline__ u16 f2b(float f) {
  union { float f; unsigned u; } x; x.f = f;
  unsigned r = x.u + 0x7fffu + ((x.u >> 16) & 1u);  // RNE
  return (u16)(r >> 16);
}
__device__ __forceinline__ float b2f(u16 h) {
  union { unsigned u; float f; } x; x.u = ((unsigned)h) << 16;
  return x.f;
}

__global__ __launch_bounds__(256)
void cast_f32_bf16(const float* __restrict__ in, u16* __restrict__ out, int n) {
  int idx = blockIdx.x * blockDim.x + threadIdx.x;
  long base = (long)idx * 8;
  if (base >= n) return;
  float4 a = *(const float4*)(in + base);
  float4 b = *(const float4*)(in + base + 4);
  u16x8 o;
  o[0] = f2b(a.x); o[1] = f2b(a.y); o[2] = f2b(a.z); o[3] = f2b(a.w);
  o[4] = f2b(b.x); o[5] = f2b(b.y); o[6] = f2b(b.z); o[7] = f2b(b.w);
  *(u16x8*)(out + base) = o;
}

// C[i,j] = alpha * sum_k A[i,k] * B[j,k]   (both row-major, K contiguous)
// grid: (N/128, M/128), block 256 (4 waves, 2x2 of 64x64 per wave)
template<bool OUT_BF16, bool CAUSAL_SKIP, bool KCLAMP>
__global__ __launch_bounds__(256)
void gemm_bt(const u16* __restrict__ A, const u16* __restrict__ B,
             void* __restrict__ C, int Kdim, int lda, int ldb, int ldc,
             float alpha) {
  const int bn = blockIdx.x, bm = blockIdx.y;
  if (CAUSAL_SKIP && bn > bm) return;  // block fully above causal diagonal

  __shared__ u16 As[128 * 32];
  __shared__ u16 Bs[128 * 32];

  const int t = threadIdx.x;
  const int w = t >> 6, l = t & 63;
  const int wr = w >> 1, wc = w & 1;
  const int lane_r = l & 15, lane_k = l >> 4;
  const int m0 = bm * 128, n0 = bn * 128;

  // staging: thread t loads 16B; LDS linear layout [row][32 bf16]
  const u16* gA = A + (size_t)(m0 + w * 16 + (l >> 2)) * lda + (l & 3) * 8;
  const u16* gB = B + (size_t)(n0 + w * 16 + (l >> 2)) * ldb + (l & 3) * 8;
  char* lA = (char*)As + w * 1024;  // wave-uniform LDS base
  char* lB = (char*)Bs + w * 1024;

  f32x4 acc[4][4] = {};

  int kend = Kdim;
  if (KCLAMP) { int kc = (bm + 1) * 128; kend = kc < Kdim ? kc : Kdim; }

  for (int k0 = 0; k0 < kend; k0 += 32) {
    __builtin_amdgcn_global_load_lds(
        (const __attribute__((address_space(1))) void*)(gA + k0),
        (__attribute__((address_space(3))) void*)(lA), 16, 0, 0);
    __builtin_amdgcn_global_load_lds(
        (const __attribute__((address_space(1))) void*)(gA + k0 + (size_t)64 * lda),
        (__attribute__((address_space(3))) void*)(lA + 4096), 16, 0, 0);
    __builtin_amdgcn_global_load_lds(
        (const __attribute__((address_space(1))) void*)(gB + k0),
        (__attribute__((address_space(3))) void*)(lB), 16, 0, 0);
    __builtin_amdgcn_global_load_lds(
        (const __attribute__((address_space(1))) void*)(gB + k0 + (size_t)64 * ldb),
        (__attribute__((address_space(3))) void*)(lB + 4096), 16, 0, 0);
    __syncthreads();

    bf16x8 af[4], bfr[4];
#pragma unroll
    for (int m = 0; m < 4; ++m)
      af[m] = *(const bf16x8*)&As[(wr * 64 + m * 16 + lane_r) * 32 + lane_k * 8];
#pragma unroll
    for (int n = 0; n < 4; ++n)
      bfr[n] = *(const bf16x8*)&Bs[(wc * 64 + n * 16 + lane_r) * 32 + lane_k * 8];
#pragma unroll
    for (int m = 0; m < 4; ++m)
#pragma unroll
      for (int n = 0; n < 4; ++n)
        acc[m][n] = __builtin_amdgcn_mfma_f32_16x16x32_bf16(af[m], bfr[n], acc[m][n], 0, 0, 0);
    __syncthreads();
  }

  // C/D layout: col = lane&15, row = (lane>>4)*4 + reg
  const int row0 = m0 + wr * 64 + lane_k * 4;
  const int col0 = n0 + wc * 64 + lane_r;
  if (OUT_BF16) {
    u16* Co = (u16*)C;
#pragma unroll
    for (int m = 0; m < 4; ++m)
#pragma unroll
      for (int n = 0; n < 4; ++n)
#pragma unroll
        for (int j = 0; j < 4; ++j)
          Co[(size_t)(row0 + m * 16 + j) * ldc + col0 + n * 16] =
              f2b(acc[m][n][j] * alpha);
  } else {
    float* Co = (float*)C;
#pragma unroll
    for (int m = 0; m < 4; ++m)
#pragma unroll
      for (int n = 0; n < 4; ++n)
#pragma unroll
        for (int j = 0; j < 4; ++j)
          Co[(size_t)(row0 + m * 16 + j) * ldc + col0 + n * 16] =
              acc[m][n][j] * alpha;
  }
}

// In-place causal row softmax over bf16 [4096][4096]; writes 0 above diagonal.
__global__ __launch_bounds__(256)
void softmax_causal(u16* __restrict__ S) {
  const int i = blockIdx.x;
  const int t = threadIdx.x;
  u16* row = S + (size_t)i * 4096;

  u16x8 r0 = *(const u16x8*)(row + t * 16);
  u16x8 r1 = *(const u16x8*)(row + t * 16 + 8);

  float v[16];
  float mx = -__builtin_inff();
#pragma unroll
  for (int c = 0; c < 16; ++c) {
    int j = t * 16 + c;
    float x = b2f(c < 8 ? r0[c] : r1[c - 8]);
    v[c] = (j <= i) ? x : -__builtin_inff();
    mx = fmaxf(mx, v[c]);
  }
#pragma unroll
  for (int off = 32; off >= 1; off >>= 1) mx = fmaxf(mx, __shfl_xor(mx, off));
  __shared__ float red[8];
  if ((t & 63) == 0) red[t >> 6] = mx;
  __syncthreads();
  mx = fmaxf(fmaxf(red[0], red[1]), fmaxf(red[2], red[3]));

  float s = 0.f;
#pragma unroll
  for (int c = 0; c < 16; ++c) {
    float e = exp2f((v[c] - mx) * 1.4426950408889634f);
    v[c] = e;
    s += e;
  }
#pragma unroll
  for (int off = 32; off >= 1; off >>= 1) s += __shfl_xor(s, off);
  if ((t & 63) == 0) red[4 + (t >> 6)] = s;
  __syncthreads();
  s = red[4] + red[5] + red[6] + red[7];
  float inv = 1.0f / s;

  u16x8 o0, o1;
#pragma unroll
  for (int c = 0; c < 8; ++c) {
    o0[c] = f2b(v[c] * inv);
    o1[c] = f2b(v[c + 8] * inv);
  }
  *(u16x8*)(row + t * 16) = o0;
  *(u16x8*)(row + t * 16 + 8) = o1;
}

extern "C" void kernel_launch(void* const* d_in, const int* in_sizes, int n_in,
                              void* d_out, int out_size, void* d_ws, size_t ws_size,
                              hipStream_t stream) {
  const float* x  = (const float*)d_in[0];
  const float* wq = (const float*)d_in[1];
  const float* wk = (const float*)d_in[2];
  const float* wv = (const float*)d_in[3];

  // workspace layout (bf16 elements); total 104 MB
  u16* x_bf  = (u16*)d_ws;
  u16* wq_bf = x_bf  + (size_t)4096 * 2048;
  u16* wk_bf = wq_bf + (size_t)2048 * 2048;
  u16* wv_bf = wk_bf + (size_t)2048 * 2048;
  u16* K_bf  = wv_bf + (size_t)2048 * 2048;
  u16* VT_bf = K_bf  + (size_t)4096 * 2048;
  u16* S_bf  = VT_bf + (size_t)2048 * 4096;
  u16* Q_bf  = (u16*)d_out;  // Q parked in d_out; dead before PV overwrites

  const float alpha = 0.022097086912079612f;  // 1/sqrt(2048)

  cast_f32_bf16<<<dim3(4096), 256, 0, stream>>>(x,  x_bf,  4096 * 2048);
  cast_f32_bf16<<<dim3(2048), 256, 0, stream>>>(wq, wq_bf, 2048 * 2048);
  cast_f32_bf16<<<dim3(2048), 256, 0, stream>>>(wk, wk_bf, 2048 * 2048);
  cast_f32_bf16<<<dim3(2048), 256, 0, stream>>>(wv, wv_bf, 2048 * 2048);

  // Q = x . wq^T  [4096x2048] bf16
  gemm_bt<true, false, false><<<dim3(16, 32), 256, 0, stream>>>(
      x_bf, wq_bf, Q_bf, 2048, 2048, 2048, 2048, 1.0f);
  // K = x . wk^T  [4096x2048] bf16
  gemm_bt<true, false, false><<<dim3(16, 32), 256, 0, stream>>>(
      x_bf, wk_bf, K_bf, 2048, 2048, 2048, 2048, 1.0f);
  // V^T = wv . x^T  [2048x4096] bf16
  gemm_bt<true, false, false><<<dim3(32, 16), 256, 0, stream>>>(
      wv_bf, x_bf, VT_bf, 2048, 2048, 2048, 4096, 1.0f);
  // S = alpha * Q . K^T  [4096x4096] bf16, causal block skip
  gemm_bt<true, true, false><<<dim3(32, 32), 256, 0, stream>>>(
      Q_bf, K_bf, S_bf, 2048, 2048, 2048, 4096, alpha);
  // row softmax with causal mask, in place
  softmax_causal<<<dim3(4096), 256, 0, stream>>>(S_bf);
  // O = P . V  [4096x2048] f32, K clamped to (bm+1)*128
  gemm_bt<false, false, true><<<dim3(16, 32), 256, 0, stream>>>(
      S_bf, VT_bf, d_out, 4096, 4096, 4096, 2048, 1.0f);
}

// Round 2
// 318.985 us; speedup vs baseline: 1.1877x; 1.1877x over previous
//
#include <hip/hip_runtime.h>

// SelfAttention: S=4096, EMB=2048, DQ=DV=2048, causal softmax(QK^T/sqrt(DQ))V
// Round 2: 2-phase double-buffered GEMM (T3-minimum) + fused QKV projection
// (N=6144 grid) with transposed-V epilogue. bf16 MFMA 16x16x32, 128x128 tile.

using u16 = unsigned short;
typedef __bf16 bf16x8 __attribute__((ext_vector_type(8)));
typedef float  f32x4  __attribute__((ext_vector_type(4)));
typedef u16    u16x8  __attribute__((ext_vector_type(8)));

__device__ __forceinline__ u16 f2b(float f) {
  union { float f; unsigned u; } x; x.f = f;
  unsigned r = x.u + 0x7fffu + ((x.u >> 16) & 1u);  // RNE
  return (u16)(r >> 16);
}
__device__ __forceinline__ float b2f(u16 h) {
  union { unsigned u; float f; } x; x.u = ((unsigned)h) << 16;
  return x.f;
}

__global__ __launch_bounds__(256)
void cast_f32_bf16(const float* __restrict__ in, u16* __restrict__ out, int n) {
  int idx = blockIdx.x * blockDim.x + threadIdx.x;
  long base = (long)idx * 8;
  if (base >= n) return;
  float4 a = *(const float4*)(in + base);
  float4 b = *(const float4*)(in + base + 4);
  u16x8 o;
  o[0] = f2b(a.x); o[1] = f2b(a.y); o[2] = f2b(a.z); o[3] = f2b(a.w);
  o[4] = f2b(b.x); o[5] = f2b(b.y); o[6] = f2b(b.z); o[7] = f2b(b.w);
  *(u16x8*)(out + base) = o;
}

// C[i,j] = alpha * sum_k A[i,k] * B[j,k]   (both row-major, K contiguous)
// grid: (N/128, M/128), block 256 (4 waves, 2x2 of 64x64 per wave)
// OUTMODE: 0 = f32 C, 1 = bf16 C, 2 = fused QKV split (Q|K normal, V transposed)
template<int OUTMODE, bool CAUSAL_SKIP, bool KCLAMP>
__global__ __launch_bounds__(256)
void gemm_bt(const u16* __restrict__ A, const u16* __restrict__ B,
             void* __restrict__ C, int Kdim, int lda, int ldb, int ldc,
             float alpha, u16* __restrict__ Kout, u16* __restrict__ VTout) {
  const int bn = blockIdx.x, bm = blockIdx.y;
  if (CAUSAL_SKIP && bn > bm) return;  // block fully above causal diagonal

  __shared__ u16 As[2][128 * 32];
  __shared__ u16 Bs[2][128 * 32];

  const int t = threadIdx.x;
  const int w = t >> 6, l = t & 63;
  const int wr = w >> 1, wc = w & 1;
  const int lane_r = l & 15, lane_k = l >> 4;
  const int m0 = bm * 128, n0 = bn * 128;

  // staging: thread t loads 16B; LDS linear layout [row][32 bf16]
  const u16* gA = A + (size_t)(m0 + w * 16 + (l >> 2)) * lda + (l & 3) * 8;
  const u16* gB = B + (size_t)(n0 + w * 16 + (l >> 2)) * ldb + (l & 3) * 8;

  f32x4 acc[4][4] = {};

  int kend = Kdim;
  if (KCLAMP) { int kc = (bm + 1) * 128; kend = kc < Kdim ? kc : Kdim; }
  const int nt = kend >> 5;

  auto stage = [&](int buf, int k0) {
    char* lA = (char*)&As[buf][0] + w * 1024;  // wave-uniform LDS base
    char* lB = (char*)&Bs[buf][0] + w * 1024;
    __builtin_amdgcn_global_load_lds(
        (const __attribute__((address_space(1))) void*)(gA + k0),
        (__attribute__((address_space(3))) void*)(lA), 16, 0, 0);
    __builtin_amdgcn_global_load_lds(
        (const __attribute__((address_space(1))) void*)(gA + k0 + (size_t)64 * lda),
        (__attribute__((address_space(3))) void*)(lA + 4096), 16, 0, 0);
    __builtin_amdgcn_global_load_lds(
        (const __attribute__((address_space(1))) void*)(gB + k0),
        (__attribute__((address_space(3))) void*)(lB), 16, 0, 0);
    __builtin_amdgcn_global_load_lds(
        (const __attribute__((address_space(1))) void*)(gB + k0 + (size_t)64 * ldb),
        (__attribute__((address_space(3))) void*)(lB + 4096), 16, 0, 0);
  };

  // prologue: fill buffer 0, single drain
  stage(0, 0);
  __syncthreads();

  int cur = 0;
  for (int tt = 0; tt < nt; ++tt) {
    if (tt + 1 < nt) stage(cur ^ 1, (tt + 1) << 5);  // prefetch next K-tile

    bf16x8 af[4], bfr[4];
#pragma unroll
    for (int m = 0; m < 4; ++m)
      af[m] = *(const bf16x8*)&As[cur][(wr * 64 + m * 16 + lane_r) * 32 + lane_k * 8];
#pragma unroll
    for (int n = 0; n < 4; ++n)
      bfr[n] = *(const bf16x8*)&Bs[cur][(wc * 64 + n * 16 + lane_r) * 32 + lane_k * 8];
#pragma unroll
    for (int m = 0; m < 4; ++m)
#pragma unroll
      for (int n = 0; n < 4; ++n)
        acc[m][n] = __builtin_amdgcn_mfma_f32_16x16x32_bf16(af[m], bfr[n], acc[m][n], 0, 0, 0);

    __syncthreads();  // implicit vmcnt(0): prefetched tile landed; reads of cur done
    cur ^= 1;
  }

  // C/D layout: col = lane&15, row = (lane>>4)*4 + reg
  const int row0 = m0 + wr * 64 + lane_k * 4;
  const int col0 = n0 + wc * 64 + lane_r;
  if (OUTMODE == 0) {
    float* Co = (float*)C;
#pragma unroll
    for (int m = 0; m < 4; ++m)
#pragma unroll
      for (int n = 0; n < 4; ++n)
#pragma unroll
        for (int j = 0; j < 4; ++j)
          Co[(size_t)(row0 + m * 16 + j) * ldc + col0 + n * 16] =
              acc[m][n][j] * alpha;
  } else if (OUTMODE == 1) {
    u16* Co = (u16*)C;
#pragma unroll
    for (int m = 0; m < 4; ++m)
#pragma unroll
      for (int n = 0; n < 4; ++n)
#pragma unroll
        for (int j = 0; j < 4; ++j)
          Co[(size_t)(row0 + m * 16 + j) * ldc + col0 + n * 16] =
              f2b(acc[m][n][j] * alpha);
  } else {
    // fused QKV: global col in [0,6144). bn<16 -> Q, bn<32 -> K, else V^T.
    if (bn < 16) {
      u16* Co = (u16*)C;
#pragma unroll
      for (int m = 0; m < 4; ++m)
#pragma unroll
        for (int n = 0; n < 4; ++n)
#pragma unroll
          for (int j = 0; j < 4; ++j)
            Co[(size_t)(row0 + m * 16 + j) * 2048 + col0 + n * 16] =
                f2b(acc[m][n][j]);
    } else if (bn < 32) {
#pragma unroll
      for (int m = 0; m < 4; ++m)
#pragma unroll
        for (int n = 0; n < 4; ++n)
#pragma unroll
          for (int j = 0; j < 4; ++j)
            Kout[(size_t)(row0 + m * 16 + j) * 2048 + (col0 + n * 16 - 2048)] =
                f2b(acc[m][n][j]);
    } else {
#pragma unroll
      for (int m = 0; m < 4; ++m)
#pragma unroll
        for (int n = 0; n < 4; ++n)
#pragma unroll
          for (int j = 0; j < 4; ++j)
            VTout[(size_t)(col0 + n * 16 - 4096) * 4096 + row0 + m * 16 + j] =
                f2b(acc[m][n][j]);
    }
  }
}

// In-place causal row softmax over bf16 [4096][4096]; writes 0 above diagonal.
__global__ __launch_bounds__(256)
void softmax_causal(u16* __restrict__ S) {
  const int i = blockIdx.x;
  const int t = threadIdx.x;
  u16* row = S + (size_t)i * 4096;

  u16x8 r0 = *(const u16x8*)(row + t * 16);
  u16x8 r1 = *(const u16x8*)(row + t * 16 + 8);

  float v[16];
  float mx = -__builtin_inff();
#pragma unroll
  for (int c = 0; c < 16; ++c) {
    int j = t * 16 + c;
    float x = b2f(c < 8 ? r0[c] : r1[c - 8]);
    v[c] = (j <= i) ? x : -__builtin_inff();
    mx = fmaxf(mx, v[c]);
  }
#pragma unroll
  for (int off = 32; off >= 1; off >>= 1) mx = fmaxf(mx, __shfl_xor(mx, off));
  __shared__ float red[8];
  if ((t & 63) == 0) red[t >> 6] = mx;
  __syncthreads();
  mx = fmaxf(fmaxf(red[0], red[1]), fmaxf(red[2], red[3]));

  float s = 0.f;
#pragma unroll
  for (int c = 0; c < 16; ++c) {
    float e = exp2f((v[c] - mx) * 1.4426950408889634f);
    v[c] = e;
    s += e;
  }
#pragma unroll
  for (int off = 32; off >= 1; off >>= 1) s += __shfl_xor(s, off);
  if ((t & 63) == 0) red[4 + (t >> 6)] = s;
  __syncthreads();
  s = red[4] + red[5] + red[6] + red[7];
  float inv = 1.0f / s;

  u16x8 o0, o1;
#pragma unroll
  for (int c = 0; c < 8; ++c) {
    o0[c] = f2b(v[c] * inv);
    o1[c] = f2b(v[c + 8] * inv);
  }
  *(u16x8*)(row + t * 16) = o0;
  *(u16x8*)(row + t * 16 + 8) = o1;
}

extern "C" void kernel_launch(void* const* d_in, const int* in_sizes, int n_in,
                              void* d_out, int out_size, void* d_ws, size_t ws_size,
                              hipStream_t stream) {
  const float* x  = (const float*)d_in[0];
  const float* wq = (const float*)d_in[1];
  const float* wk = (const float*)d_in[2];
  const float* wv = (const float*)d_in[3];

  // workspace layout (bf16 elements); wq/wk/wv contiguous = W [6144][2048]
  u16* x_bf  = (u16*)d_ws;
  u16* wq_bf = x_bf  + (size_t)4096 * 2048;
  u16* wk_bf = wq_bf + (size_t)2048 * 2048;
  u16* wv_bf = wk_bf + (size_t)2048 * 2048;
  u16* K_bf  = wv_bf + (size_t)2048 * 2048;
  u16* VT_bf = K_bf  + (size_t)4096 * 2048;
  u16* S_bf  = VT_bf + (size_t)2048 * 4096;
  u16* Q_bf  = (u16*)d_out;  // Q parked in d_out; dead before PV overwrites

  const float alpha = 0.022097086912079612f;  // 1/sqrt(2048)

  cast_f32_bf16<<<dim3(4096), 256, 0, stream>>>(x,  x_bf,  4096 * 2048);
  cast_f32_bf16<<<dim3(2048), 256, 0, stream>>>(wq, wq_bf, 2048 * 2048);
  cast_f32_bf16<<<dim3(2048), 256, 0, stream>>>(wk, wk_bf, 2048 * 2048);
  cast_f32_bf16<<<dim3(2048), 256, 0, stream>>>(wv, wv_bf, 2048 * 2048);

  // fused [Q|K|V^T] = x . W^T, N=6144, grid 48x32 = 1536 blocks
  gemm_bt<2, false, false><<<dim3(48, 32), 256, 0, stream>>>(
      x_bf, wq_bf, Q_bf, 2048, 2048, 2048, 0, 1.0f, K_bf, VT_bf);
  // S = alpha * Q . K^T  [4096x4096] bf16, causal block skip
  gemm_bt<1, true, false><<<dim3(32, 32), 256, 0, stream>>>(
      Q_bf, K_bf, S_bf, 2048, 2048, 2048, 4096, alpha, nullptr, nullptr);
  // row softmax with causal mask, in place
  softmax_causal<<<dim3(4096), 256, 0, stream>>>(S_bf);
  // O = P . V  [4096x2048] f32, K clamped to (bm+1)*128
  gemm_bt<0, false, true><<<dim3(16, 32), 256, 0, stream>>>(
      S_bf, VT_bf, d_out, 4096, 4096, 4096, 2048, 1.0f, nullptr, nullptr);
}

// Round 3
// 317.970 us; speedup vs baseline: 1.1915x; 1.0032x over previous
//
#include <hip/hip_runtime.h>

// SelfAttention: S=4096, EMB=2048, DQ=DV=2048, causal softmax(QK^T/sqrt(DQ))V
// Round 3: QKV projection moved to 256x256 8-phase-style schedule (T2 swizzle +
// counted vmcnt + setprio, raw barriers). S/PV GEMMs stay 2-phase 128x128.

using u16 = unsigned short;
typedef __bf16 bf16x8 __attribute__((ext_vector_type(8)));
typedef float  f32x4  __attribute__((ext_vector_type(4)));
typedef u16    u16x8  __attribute__((ext_vector_type(8)));

__device__ __forceinline__ u16 f2b(float f) {
  union { float f; unsigned u; } x; x.f = f;
  unsigned r = x.u + 0x7fffu + ((x.u >> 16) & 1u);  // RNE
  return (u16)(r >> 16);
}
__device__ __forceinline__ float b2f(u16 h) {
  union { unsigned u; float f; } x; x.u = ((unsigned)h) << 16;
  return x.f;
}

__global__ __launch_bounds__(256)
void cast_f32_bf16(const float* __restrict__ in, u16* __restrict__ out, int n) {
  int idx = blockIdx.x * blockDim.x + threadIdx.x;
  long base = (long)idx * 8;
  if (base >= n) return;
  float4 a = *(const float4*)(in + base);
  float4 b = *(const float4*)(in + base + 4);
  u16x8 o;
  o[0] = f2b(a.x); o[1] = f2b(a.y); o[2] = f2b(a.z); o[3] = f2b(a.w);
  o[4] = f2b(b.x); o[5] = f2b(b.y); o[6] = f2b(b.z); o[7] = f2b(b.w);
  *(u16x8*)(out + base) = o;
}

#define GLL16(src, dst)                                                        \
  __builtin_amdgcn_global_load_lds(                                            \
      (const __attribute__((address_space(1))) void*)(src),                    \
      (__attribute__((address_space(3))) void*)(dst), 16, 0, 0)

// ---------------------------------------------------------------------------
// QKV: [Q|K|V^T] = x(4096x2048) . W^T(6144x2048). 256x256 tile, BK=64, 8 waves
// (2Mx4N), 4 phases/K-tile, double-buffered 128KB LDS, counted vmcnt(4),
// st-swizzle byte^=(r&7)<<4 via pre-swizzled global source + XOR'd ds_read.
// ---------------------------------------------------------------------------
__global__ __launch_bounds__(512)
void gemm_qkv_8ph(const u16* __restrict__ A, const u16* __restrict__ W,
                  u16* __restrict__ Qo, u16* __restrict__ Ko,
                  u16* __restrict__ VTo) {
  extern __shared__ u16 sm[];  // [2 buf][4 region][8192] ; regions: Ah0,Ah1,Bh0,Bh1
  constexpr int NT = 32;       // 2048 / 64
  const int bn = blockIdx.x, bm = blockIdx.y;
  const int tid = threadIdx.x;
  const int w = tid >> 6, lane = tid & 63;
  const int wr = w >> 2, wc = w & 3;       // 2 x 4 wave grid
  const int l15 = lane & 15, l4 = lane >> 4;
  const int m0 = bm * 256, n0 = bn * 256;
  const int rs = lane >> 3;                 // staged row sub-index (r&7)
  const int cs = ((lane & 7) ^ rs) << 3;    // pre-swizzled source col (bf16)

  const u16* gA = A + (size_t)(m0 + w * 8 + rs) * 2048 + cs;
  const u16* gW = W + (size_t)(n0 + w * 8 + rs) * 2048 + cs;
  u16* lw = sm + (size_t)w * 512;           // wave chunk base (1024B/chunk)

  auto stA = [&](int buf, int h, int kt) {  // stage A-half h of k-tile kt
    const u16* s = gA + (size_t)h * 128 * 2048 + kt * 64;
    u16* d = lw + (size_t)(buf * 4 + h) * 8192;
    GLL16(s, d);
    GLL16(s + (size_t)64 * 2048, d + 4096);
  };
  auto stB = [&](int buf, int h, int kt) {  // stage B-half h
    const u16* s = gW + (size_t)h * 128 * 2048 + kt * 64;
    u16* d = lw + (size_t)(buf * 4 + 2 + h) * 8192;
    GLL16(s, d);
    GLL16(s + (size_t)64 * 2048, d + 4096);
  };

  const int swz = (l15 & 7) << 3;
  auto rdA = [&](int buf, int m, int kk) -> bf16x8 {
    int idx = ((m * 16 + l15) * 64 + kk * 32 + l4 * 8) ^ swz;
    return *(const bf16x8*)&sm[(size_t)(buf * 4 + wr) * 8192 + idx];
  };
  auto rdB = [&](int buf, int n, int kk) -> bf16x8 {
    int idx = (((wc & 1) * 64 + n * 16 + l15) * 64 + kk * 32 + l4 * 8) ^ swz;
    return *(const bf16x8*)&sm[(size_t)(buf * 4 + 2 + (wc >> 1)) * 8192 + idx];
  };

  f32x4 acc[8][4] = {};
  bf16x8 a[8][2], b[4][2];

  // prologue: Bh1(0),Bh0(0),Ah0(0),Ah1(0),Bh1(1),Bh0(1); wait all of tile 0
  stB(0, 1, 0); stB(0, 0, 0); stA(0, 0, 0); stA(0, 1, 0);
  stB(1, 1, 1); stB(1, 0, 1);
  asm volatile("s_waitcnt vmcnt(4)" ::: "memory");
  __builtin_amdgcn_sched_barrier(0);
  __builtin_amdgcn_s_barrier();

  for (int t = 0; t < NT; ++t) {
    const int cur = t & 1, nxt = cur ^ 1;
    // -------- phase 0: stage Ah0(t+1) | read A m0-3, B n0-1 | MFMA q(0,0)
    if (t + 1 < NT) stA(nxt, 0, t + 1);
#pragma unroll
    for (int m = 0; m < 4; ++m) { a[m][0] = rdA(cur, m, 0); a[m][1] = rdA(cur, m, 1); }
#pragma unroll
    for (int n = 0; n < 2; ++n) { b[n][0] = rdB(cur, n, 0); b[n][1] = rdB(cur, n, 1); }
    __builtin_amdgcn_s_barrier();
    __builtin_amdgcn_s_setprio(1);
#pragma unroll
    for (int m = 0; m < 4; ++m)
#pragma unroll
      for (int n = 0; n < 2; ++n)
#pragma unroll
        for (int kk = 0; kk < 2; ++kk)
          acc[m][n] = __builtin_amdgcn_mfma_f32_16x16x32_bf16(a[m][kk], b[n][kk], acc[m][n], 0, 0, 0);
    __builtin_amdgcn_s_setprio(0);
    __builtin_amdgcn_s_barrier();
    // -------- phase 1: stage Ah1(t+1) | read B n2-3 | MFMA q(0,1)
    if (t + 1 < NT) stA(nxt, 1, t + 1);
#pragma unroll
    for (int n = 2; n < 4; ++n) { b[n][0] = rdB(cur, n, 0); b[n][1] = rdB(cur, n, 1); }
    __builtin_amdgcn_s_barrier();
    __builtin_amdgcn_s_setprio(1);
#pragma unroll
    for (int m = 0; m < 4; ++m)
#pragma unroll
      for (int n = 2; n < 4; ++n)
#pragma unroll
        for (int kk = 0; kk < 2; ++kk)
          acc[m][n] = __builtin_amdgcn_mfma_f32_16x16x32_bf16(a[m][kk], b[n][kk], acc[m][n], 0, 0, 0);
    __builtin_amdgcn_s_setprio(0);
    __builtin_amdgcn_s_barrier();
    // -------- phase 2: stage Bh1(t+2) into cur | read A m4-7 | MFMA q(1,0)
    if (t + 2 < NT) stB(cur, 1, t + 2);
#pragma unroll
    for (int m = 4; m < 8; ++m) { a[m][0] = rdA(cur, m, 0); a[m][1] = rdA(cur, m, 1); }
    __builtin_amdgcn_s_barrier();
    __builtin_amdgcn_s_setprio(1);
#pragma unroll
    for (int m = 4; m < 8; ++m)
#pragma unroll
      for (int n = 0; n < 2; ++n)
#pragma unroll
        for (int kk = 0; kk < 2; ++kk)
          acc[m][n] = __builtin_amdgcn_mfma_f32_16x16x32_bf16(a[m][kk], b[n][kk], acc[m][n], 0, 0, 0);
    __builtin_amdgcn_s_setprio(0);
    __builtin_amdgcn_s_barrier();
    // -------- phase 3: stage Bh0(t+2) into cur | MFMA q(1,1) | vmcnt(4)
    if (t + 2 < NT) stB(cur, 0, t + 2);
    __builtin_amdgcn_s_barrier();
    __builtin_amdgcn_s_setprio(1);
#pragma unroll
    for (int m = 4; m < 8; ++m)
#pragma unroll
      for (int n = 2; n < 4; ++n)
#pragma unroll
        for (int kk = 0; kk < 2; ++kk)
          acc[m][n] = __builtin_amdgcn_mfma_f32_16x16x32_bf16(a[m][kk], b[n][kk], acc[m][n], 0, 0, 0);
    __builtin_amdgcn_s_setprio(0);
    if (t + 2 < NT)      { asm volatile("s_waitcnt vmcnt(4)" ::: "memory"); }
    else if (t + 1 < NT) { asm volatile("s_waitcnt vmcnt(0)" ::: "memory"); }
    __builtin_amdgcn_sched_barrier(0);
    __builtin_amdgcn_s_barrier();
  }

  // epilogue: C/D layout col=lane&15, row=(lane>>4)*4+reg
  const int row0 = m0 + wr * 128 + l4 * 4;
  const int colg = n0 + wc * 64 + l15;
  if (bn < 8) {  // Q
#pragma unroll
    for (int m = 0; m < 8; ++m)
#pragma unroll
      for (int n = 0; n < 4; ++n)
#pragma unroll
        for (int j = 0; j < 4; ++j)
          Qo[(size_t)(row0 + m * 16 + j) * 2048 + colg + n * 16] = f2b(acc[m][n][j]);
  } else if (bn < 16) {  // K
#pragma unroll
    for (int m = 0; m < 8; ++m)
#pragma unroll
      for (int n = 0; n < 4; ++n)
#pragma unroll
        for (int j = 0; j < 4; ++j)
          Ko[(size_t)(row0 + m * 16 + j) * 2048 + (colg + n * 16 - 2048)] = f2b(acc[m][n][j]);
  } else {  // V^T
#pragma unroll
    for (int m = 0; m < 8; ++m)
#pragma unroll
      for (int n = 0; n < 4; ++n)
#pragma unroll
        for (int j = 0; j < 4; ++j)
          VTo[(size_t)(colg + n * 16 - 4096) * 4096 + row0 + m * 16 + j] = f2b(acc[m][n][j]);
  }
}

// ---------------------------------------------------------------------------
// 2-phase 128x128 GEMM (proven): C[i,j] = alpha * sum_k A[i,k]*B[j,k]
// OUT_BF16: bf16 vs f32 C. CAUSAL_SKIP: skip blocks above diag. KCLAMP: PV.
// ---------------------------------------------------------------------------
template<bool OUT_BF16, bool CAUSAL_SKIP, bool KCLAMP>
__global__ __launch_bounds__(256)
void gemm_bt(const u16* __restrict__ A, const u16* __restrict__ B,
             void* __restrict__ C, int Kdim, int lda, int ldb, int ldc,
             float alpha) {
  const int bn = blockIdx.x, bm = blockIdx.y;
  if (CAUSAL_SKIP && bn > bm) return;

  __shared__ u16 As[2][128 * 32];
  __shared__ u16 Bs[2][128 * 32];

  const int t = threadIdx.x;
  const int w = t >> 6, l = t & 63;
  const int wr = w >> 1, wc = w & 1;
  const int lane_r = l & 15, lane_k = l >> 4;
  const int m0 = bm * 128, n0 = bn * 128;

  const u16* gA = A + (size_t)(m0 + w * 16 + (l >> 2)) * lda + (l & 3) * 8;
  const u16* gB = B + (size_t)(n0 + w * 16 + (l >> 2)) * ldb + (l & 3) * 8;

  f32x4 acc[4][4] = {};

  int kend = Kdim;
  if (KCLAMP) { int kc = (bm + 1) * 128; kend = kc < Kdim ? kc : Kdim; }
  const int nt = kend >> 5;

  auto stage = [&](int buf, int k0) {
    char* lA = (char*)&As[buf][0] + w * 1024;
    char* lB = (char*)&Bs[buf][0] + w * 1024;
    GLL16(gA + k0, lA);
    GLL16(gA + k0 + (size_t)64 * lda, lA + 4096);
    GLL16(gB + k0, lB);
    GLL16(gB + k0 + (size_t)64 * ldb, lB + 4096);
  };

  stage(0, 0);
  __syncthreads();

  int cur = 0;
  for (int tt = 0; tt < nt; ++tt) {
    if (tt + 1 < nt) stage(cur ^ 1, (tt + 1) << 5);

    bf16x8 af[4], bfr[4];
#pragma unroll
    for (int m = 0; m < 4; ++m)
      af[m] = *(const bf16x8*)&As[cur][(wr * 64 + m * 16 + lane_r) * 32 + lane_k * 8];
#pragma unroll
    for (int n = 0; n < 4; ++n)
      bfr[n] = *(const bf16x8*)&Bs[cur][(wc * 64 + n * 16 + lane_r) * 32 + lane_k * 8];
#pragma unroll
    for (int m = 0; m < 4; ++m)
#pragma unroll
      for (int n = 0; n < 4; ++n)
        acc[m][n] = __builtin_amdgcn_mfma_f32_16x16x32_bf16(af[m], bfr[n], acc[m][n], 0, 0, 0);

    __syncthreads();
    cur ^= 1;
  }

  const int row0 = m0 + wr * 64 + lane_k * 4;
  const int col0 = n0 + wc * 64 + lane_r;
  if (OUT_BF16) {
    u16* Co = (u16*)C;
#pragma unroll
    for (int m = 0; m < 4; ++m)
#pragma unroll
      for (int n = 0; n < 4; ++n)
#pragma unroll
        for (int j = 0; j < 4; ++j)
          Co[(size_t)(row0 + m * 16 + j) * ldc + col0 + n * 16] = f2b(acc[m][n][j] * alpha);
  } else {
    float* Co = (float*)C;
#pragma unroll
    for (int m = 0; m < 4; ++m)
#pragma unroll
      for (int n = 0; n < 4; ++n)
#pragma unroll
        for (int j = 0; j < 4; ++j)
          Co[(size_t)(row0 + m * 16 + j) * ldc + col0 + n * 16] = acc[m][n][j] * alpha;
  }
}

// In-place causal row softmax over bf16 [4096][4096]; writes 0 above diagonal.
__global__ __launch_bounds__(256)
void softmax_causal(u16* __restrict__ S) {
  const int i = blockIdx.x;
  const int t = threadIdx.x;
  u16* row = S + (size_t)i * 4096;

  u16x8 r0 = *(const u16x8*)(row + t * 16);
  u16x8 r1 = *(const u16x8*)(row + t * 16 + 8);

  float v[16];
  float mx = -__builtin_inff();
#pragma unroll
  for (int c = 0; c < 16; ++c) {
    int j = t * 16 + c;
    float x = b2f(c < 8 ? r0[c] : r1[c - 8]);
    v[c] = (j <= i) ? x : -__builtin_inff();
    mx = fmaxf(mx, v[c]);
  }
#pragma unroll
  for (int off = 32; off >= 1; off >>= 1) mx = fmaxf(mx, __shfl_xor(mx, off));
  __shared__ float red[8];
  if ((t & 63) == 0) red[t >> 6] = mx;
  __syncthreads();
  mx = fmaxf(fmaxf(red[0], red[1]), fmaxf(red[2], red[3]));

  float s = 0.f;
#pragma unroll
  for (int c = 0; c < 16; ++c) {
    float e = exp2f((v[c] - mx) * 1.4426950408889634f);
    v[c] = e;
    s += e;
  }
#pragma unroll
  for (int off = 32; off >= 1; off >>= 1) s += __shfl_xor(s, off);
  if ((t & 63) == 0) red[4 + (t >> 6)] = s;
  __syncthreads();
  s = red[4] + red[5] + red[6] + red[7];
  float inv = 1.0f / s;

  u16x8 o0, o1;
#pragma unroll
  for (int c = 0; c < 8; ++c) {
    o0[c] = f2b(v[c] * inv);
    o1[c] = f2b(v[c + 8] * inv);
  }
  *(u16x8*)(row + t * 16) = o0;
  *(u16x8*)(row + t * 16 + 8) = o1;
}

extern "C" void kernel_launch(void* const* d_in, const int* in_sizes, int n_in,
                              void* d_out, int out_size, void* d_ws, size_t ws_size,
                              hipStream_t stream) {
  const float* x  = (const float*)d_in[0];
  const float* wq = (const float*)d_in[1];
  const float* wk = (const float*)d_in[2];
  const float* wv = (const float*)d_in[3];

  // workspace layout (bf16 elements); wq/wk/wv contiguous = W [6144][2048]
  u16* x_bf  = (u16*)d_ws;
  u16* wq_bf = x_bf  + (size_t)4096 * 2048;
  u16* wk_bf = wq_bf + (size_t)2048 * 2048;
  u16* wv_bf = wk_bf + (size_t)2048 * 2048;
  u16* K_bf  = wv_bf + (size_t)2048 * 2048;
  u16* VT_bf = K_bf  + (size_t)4096 * 2048;
  u16* S_bf  = VT_bf + (size_t)2048 * 4096;
  u16* Q_bf  = (u16*)d_out;  // Q parked in d_out; dead before PV overwrites

  const float alpha = 0.022097086912079612f;  // 1/sqrt(2048)

  cast_f32_bf16<<<dim3(4096), 256, 0, stream>>>(x,  x_bf,  4096 * 2048);
  cast_f32_bf16<<<dim3(2048), 256, 0, stream>>>(wq, wq_bf, 2048 * 2048);
  cast_f32_bf16<<<dim3(2048), 256, 0, stream>>>(wk, wk_bf, 2048 * 2048);
  cast_f32_bf16<<<dim3(2048), 256, 0, stream>>>(wv, wv_bf, 2048 * 2048);

  // fused [Q|K|V^T] = x . W^T  (256x256 tiles, 8-phase schedule, 128KB LDS)
  gemm_qkv_8ph<<<dim3(24, 16), 512, 131072, stream>>>(
      x_bf, wq_bf, Q_bf, K_bf, VT_bf);
  // S = alpha * Q . K^T  [4096x4096] bf16, causal block skip
  gemm_bt<true, true, false><<<dim3(32, 32), 256, 0, stream>>>(
      Q_bf, K_bf, S_bf, 2048, 2048, 2048, 4096, alpha);
  // row softmax with causal mask, in place
  softmax_causal<<<dim3(4096), 256, 0, stream>>>(S_bf);
  // O = P . V  [4096x2048] f32, K clamped to (bm+1)*128
  gemm_bt<false, false, true><<<dim3(16, 32), 256, 0, stream>>>(
      S_bf, VT_bf, d_out, 4096, 4096, 4096, 2048, 1.0f);
}

// Round 4
// 308.603 us; speedup vs baseline: 1.2277x; 1.0304x over previous
//
#include <hip/hip_runtime.h>

// SelfAttention: S=4096, EMB=2048, DQ=DV=2048, causal softmax(QK^T/sqrt(DQ))V
// Round 4: QKV as 256x128-tile, 8-wave, BK=64, 2-phase/K-tile read-ahead
// pipeline (reads issued one full phase before consumption), counted vmcnt(6),
// T2 swizzle, grid 768 = exactly 3 blocks/CU (zero tail). S/PV stay 2ph 128².

using u16 = unsigned short;
typedef __bf16 bf16x8 __attribute__((ext_vector_type(8)));
typedef float  f32x4  __attribute__((ext_vector_type(4)));
typedef u16    u16x8  __attribute__((ext_vector_type(8)));

__device__ __forceinline__ u16 f2b(float f) {
  union { float f; unsigned u; } x; x.f = f;
  unsigned r = x.u + 0x7fffu + ((x.u >> 16) & 1u);  // RNE
  return (u16)(r >> 16);
}
__device__ __forceinline__ float b2f(u16 h) {
  union { unsigned u; float f; } x; x.u = ((unsigned)h) << 16;
  return x.f;
}

__global__ __launch_bounds__(256)
void cast_f32_bf16(const float* __restrict__ in, u16* __restrict__ out, int n) {
  int idx = blockIdx.x * blockDim.x + threadIdx.x;
  long base = (long)idx * 8;
  if (base >= n) return;
  float4 a = *(const float4*)(in + base);
  float4 b = *(const float4*)(in + base + 4);
  u16x8 o;
  o[0] = f2b(a.x); o[1] = f2b(a.y); o[2] = f2b(a.z); o[3] = f2b(a.w);
  o[4] = f2b(b.x); o[5] = f2b(b.y); o[6] = f2b(b.z); o[7] = f2b(b.w);
  *(u16x8*)(out + base) = o;
}

#define GLL16(src, dst)                                                        \
  __builtin_amdgcn_global_load_lds(                                            \
      (const __attribute__((address_space(1))) void*)(src),                    \
      (__attribute__((address_space(3))) void*)(dst), 16, 0, 0)

#define MFMA_BF16(a, b, c) __builtin_amdgcn_mfma_f32_16x16x32_bf16(a, b, c, 0, 0, 0)

// ---------------------------------------------------------------------------
// QKV: [Q|K|V^T] = x(4096x2048) . W^T(6144x2048).
// Tile 256x128 (BMxBN), BK=64, 8 waves as 4Mx2N (wave tile 64x64).
// Grid 48x16 = 768 blocks = 3/CU exact. LDS 96KB double-buffered:
//   per buf: A units 0..3 (64 rows x 64 bf16 = 8KB each), B units 0..1.
// Pipeline: stages during tile t fill parity-buf(t) for tile t+2.
//   ph0(t): stage A0-2(t+2) | read B23(t)        | bar | MFMA c0 (A(t)xB01(t)) | lgkm0 | bar
//   ph1(t): stage A3,B0,B1(t+2) | vmcnt(6) | bar | read A(t+1)+B01(t+1) | MFMA c1 (A(t)xB23(t)) | lgkm0 | bar
// Every read is consumed one phase later -> no MFMA waits on fresh ds_reads.
// ---------------------------------------------------------------------------
__global__ __launch_bounds__(512)
void gemm_qkv(const u16* __restrict__ A, const u16* __restrict__ W,
              u16* __restrict__ Qo, u16* __restrict__ Ko,
              u16* __restrict__ VTo) {
  extern __shared__ char lds[];
  constexpr int NT = 32;  // 2048/64
  const int bn = blockIdx.x, bm = blockIdx.y;
  const int tid = threadIdx.x;
  const int w = tid >> 6, lane = tid & 63;
  const int wr = w >> 1, wc = w & 1;
  const int l15 = lane & 15, l4 = lane >> 4;
  const int rs = lane >> 3;                 // staged row sub-index (row&7)
  const int csw = ((lane & 7) ^ rs) << 3;   // pre-swizzled source col (bf16)
  const int m0 = bm * 256, n0 = bn * 128;

  const u16* gA = A + (size_t)(m0 + w * 8 + rs) * 2048 + csw;
  const u16* gB = W + (size_t)(n0 + w * 8 + rs) * 2048 + csw;
  char* lw = lds + w * 1024;
  const u16* sm = (const u16*)lds;

  auto stA = [&](int p, int u, int tt) {
    GLL16(gA + (size_t)u * 64 * 2048 + tt * 64, lw + p * 49152 + u * 8192);
  };
  auto stB = [&](int p, int u, int tt) {
    GLL16(gB + (size_t)u * 64 * 2048 + tt * 64, lw + p * 49152 + 32768 + u * 8192);
  };
  const int swz = (l15 & 7) << 3;
  auto rdA = [&](int p, int m, int kk) -> bf16x8 {
    int e = p * 24576 + wr * 4096 + (((m * 16 + l15) * 64 + kk * 32 + l4 * 8) ^ swz);
    return *(const bf16x8*)&sm[e];
  };
  auto rdB = [&](int p, int n, int kk) -> bf16x8 {
    int e = p * 24576 + 16384 + wc * 4096 +
            (((n * 16 + l15) * 64 + kk * 32 + l4 * 8) ^ swz);
    return *(const bf16x8*)&sm[e];
  };

  f32x4 acc[4][4] = {};
  bf16x8 aE[4][2], aO[4][2], b01E[2][2], b01O[2][2], b23E[2][2], b23O[2][2];

  // prologue: stage tiles 0 (buf0) and 1 (buf1); drain tile 0; read A(0),B01(0)
  stA(0,0,0); stA(0,1,0); stA(0,2,0); stA(0,3,0); stB(0,0,0); stB(0,1,0);
  stA(1,0,1); stA(1,1,1); stA(1,2,1); stA(1,3,1); stB(1,0,1); stB(1,1,1);
  asm volatile("s_waitcnt vmcnt(6)" ::: "memory");
  __builtin_amdgcn_sched_barrier(0);
  __builtin_amdgcn_s_barrier();
#pragma unroll
  for (int m = 0; m < 4; ++m) { aE[m][0] = rdA(0,m,0); aE[m][1] = rdA(0,m,1); }
#pragma unroll
  for (int n = 0; n < 2; ++n) { b01E[n][0] = rdB(0,n,0); b01E[n][1] = rdB(0,n,1); }
  asm volatile("s_waitcnt lgkmcnt(0)" ::: "memory");
  __builtin_amdgcn_sched_barrier(0);
  __builtin_amdgcn_s_barrier();

  for (int i = 0; i < NT / 2; ++i) {
    const int te = 2 * i, to = 2 * i + 1;
    // ================= tile te (buf0) =================
    // ---- ph0 ----
    if (te + 2 < NT) { stA(0,0,te+2); stA(0,1,te+2); stA(0,2,te+2); }
#pragma unroll
    for (int n = 0; n < 2; ++n) { b23E[n][0] = rdB(0,n+2,0); b23E[n][1] = rdB(0,n+2,1); }
    __builtin_amdgcn_s_barrier();
    __builtin_amdgcn_s_setprio(1);
#pragma unroll
    for (int m = 0; m < 4; ++m)
#pragma unroll
      for (int n = 0; n < 2; ++n)
#pragma unroll
        for (int kk = 0; kk < 2; ++kk)
          acc[m][n] = MFMA_BF16(aE[m][kk], b01E[n][kk], acc[m][n]);
    __builtin_amdgcn_s_setprio(0);
    asm volatile("s_waitcnt lgkmcnt(0)" ::: "memory");
    __builtin_amdgcn_sched_barrier(0);
    __builtin_amdgcn_s_barrier();
    // ---- ph1 ----
    if (te + 2 < NT) {
      stA(0,3,te+2); stB(0,0,te+2); stB(0,1,te+2);
      asm volatile("s_waitcnt vmcnt(6)" ::: "memory");
    } else {
      asm volatile("s_waitcnt vmcnt(0)" ::: "memory");
    }
    __builtin_amdgcn_sched_barrier(0);
    __builtin_amdgcn_s_barrier();
#pragma unroll
    for (int m = 0; m < 4; ++m) { aO[m][0] = rdA(1,m,0); aO[m][1] = rdA(1,m,1); }
#pragma unroll
    for (int n = 0; n < 2; ++n) { b01O[n][0] = rdB(1,n,0); b01O[n][1] = rdB(1,n,1); }
    __builtin_amdgcn_s_setprio(1);
#pragma unroll
    for (int m = 0; m < 4; ++m)
#pragma unroll
      for (int n = 0; n < 2; ++n)
#pragma unroll
        for (int kk = 0; kk < 2; ++kk)
          acc[m][n+2] = MFMA_BF16(aE[m][kk], b23E[n][kk], acc[m][n+2]);
    __builtin_amdgcn_s_setprio(0);
    asm volatile("s_waitcnt lgkmcnt(0)" ::: "memory");
    __builtin_amdgcn_sched_barrier(0);
    __builtin_amdgcn_s_barrier();
    // ================= tile to (buf1) =================
    // ---- ph0 ----
    if (to + 2 < NT) { stA(1,0,to+2); stA(1,1,to+2); stA(1,2,to+2); }
#pragma unroll
    for (int n = 0; n < 2; ++n) { b23O[n][0] = rdB(1,n+2,0); b23O[n][1] = rdB(1,n+2,1); }
    __builtin_amdgcn_s_barrier();
    __builtin_amdgcn_s_setprio(1);
#pragma unroll
    for (int m = 0; m < 4; ++m)
#pragma unroll
      for (int n = 0; n < 2; ++n)
#pragma unroll
        for (int kk = 0; kk < 2; ++kk)
          acc[m][n] = MFMA_BF16(aO[m][kk], b01O[n][kk], acc[m][n]);
    __builtin_amdgcn_s_setprio(0);
    asm volatile("s_waitcnt lgkmcnt(0)" ::: "memory");
    __builtin_amdgcn_sched_barrier(0);
    __builtin_amdgcn_s_barrier();
    // ---- ph1 ----
    if (to + 2 < NT) {
      stA(1,3,to+2); stB(1,0,to+2); stB(1,1,to+2);
      asm volatile("s_waitcnt vmcnt(6)" ::: "memory");
    } else if (to + 1 < NT) {
      asm volatile("s_waitcnt vmcnt(0)" ::: "memory");
    }
    __builtin_amdgcn_sched_barrier(0);
    __builtin_amdgcn_s_barrier();
    if (to + 1 < NT) {
#pragma unroll
      for (int m = 0; m < 4; ++m) { aE[m][0] = rdA(0,m,0); aE[m][1] = rdA(0,m,1); }
#pragma unroll
      for (int n = 0; n < 2; ++n) { b01E[n][0] = rdB(0,n,0); b01E[n][1] = rdB(0,n,1); }
    }
    __builtin_amdgcn_s_setprio(1);
#pragma unroll
    for (int m = 0; m < 4; ++m)
#pragma unroll
      for (int n = 0; n < 2; ++n)
#pragma unroll
        for (int kk = 0; kk < 2; ++kk)
          acc[m][n+2] = MFMA_BF16(aO[m][kk], b23O[n][kk], acc[m][n+2]);
    __builtin_amdgcn_s_setprio(0);
    asm volatile("s_waitcnt lgkmcnt(0)" ::: "memory");
    __builtin_amdgcn_sched_barrier(0);
    __builtin_amdgcn_s_barrier();
  }

  // epilogue: C/D layout col=lane&15, row=(lane>>4)*4+reg
  const int row0 = m0 + wr * 64 + l4 * 4;
  const int cg0 = n0 + wc * 64 + l15;
  if (bn < 16) {  // Q
#pragma unroll
    for (int m = 0; m < 4; ++m)
#pragma unroll
      for (int n = 0; n < 4; ++n)
#pragma unroll
        for (int j = 0; j < 4; ++j)
          Qo[(size_t)(row0 + m * 16 + j) * 2048 + cg0 + n * 16] = f2b(acc[m][n][j]);
  } else if (bn < 32) {  // K
#pragma unroll
    for (int m = 0; m < 4; ++m)
#pragma unroll
      for (int n = 0; n < 4; ++n)
#pragma unroll
        for (int j = 0; j < 4; ++j)
          Ko[(size_t)(row0 + m * 16 + j) * 2048 + (cg0 + n * 16 - 2048)] = f2b(acc[m][n][j]);
  } else {  // V^T
#pragma unroll
    for (int m = 0; m < 4; ++m)
#pragma unroll
      for (int n = 0; n < 4; ++n)
#pragma unroll
        for (int j = 0; j < 4; ++j)
          VTo[(size_t)(cg0 + n * 16 - 4096) * 4096 + row0 + m * 16 + j] = f2b(acc[m][n][j]);
  }
}

// ---------------------------------------------------------------------------
// 2-phase 128x128 GEMM (proven): C[i,j] = alpha * sum_k A[i,k]*B[j,k]
// ---------------------------------------------------------------------------
template<bool OUT_BF16, bool CAUSAL_SKIP, bool KCLAMP>
__global__ __launch_bounds__(256)
void gemm_bt(const u16* __restrict__ A, const u16* __restrict__ B,
             void* __restrict__ C, int Kdim, int lda, int ldb, int ldc,
             float alpha) {
  const int bn = blockIdx.x, bm = blockIdx.y;
  if (CAUSAL_SKIP && bn > bm) return;

  __shared__ u16 As[2][128 * 32];
  __shared__ u16 Bs[2][128 * 32];

  const int t = threadIdx.x;
  const int w = t >> 6, l = t & 63;
  const int wr = w >> 1, wc = w & 1;
  const int lane_r = l & 15, lane_k = l >> 4;
  const int m0 = bm * 128, n0 = bn * 128;

  const u16* gA = A + (size_t)(m0 + w * 16 + (l >> 2)) * lda + (l & 3) * 8;
  const u16* gB = B + (size_t)(n0 + w * 16 + (l >> 2)) * ldb + (l & 3) * 8;

  f32x4 acc[4][4] = {};

  int kend = Kdim;
  if (KCLAMP) { int kc = (bm + 1) * 128; kend = kc < Kdim ? kc : Kdim; }
  const int nt = kend >> 5;

  auto stage = [&](int buf, int k0) {
    char* lA = (char*)&As[buf][0] + w * 1024;
    char* lB = (char*)&Bs[buf][0] + w * 1024;
    GLL16(gA + k0, lA);
    GLL16(gA + k0 + (size_t)64 * lda, lA + 4096);
    GLL16(gB + k0, lB);
    GLL16(gB + k0 + (size_t)64 * ldb, lB + 4096);
  };

  stage(0, 0);
  __syncthreads();

  int cur = 0;
  for (int tt = 0; tt < nt; ++tt) {
    if (tt + 1 < nt) stage(cur ^ 1, (tt + 1) << 5);

    bf16x8 af[4], bfr[4];
#pragma unroll
    for (int m = 0; m < 4; ++m)
      af[m] = *(const bf16x8*)&As[cur][(wr * 64 + m * 16 + lane_r) * 32 + lane_k * 8];
#pragma unroll
    for (int n = 0; n < 4; ++n)
      bfr[n] = *(const bf16x8*)&Bs[cur][(wc * 64 + n * 16 + lane_r) * 32 + lane_k * 8];
#pragma unroll
    for (int m = 0; m < 4; ++m)
#pragma unroll
      for (int n = 0; n < 4; ++n)
        acc[m][n] = MFMA_BF16(af[m], bfr[n], acc[m][n]);

    __syncthreads();
    cur ^= 1;
  }

  const int row0 = m0 + wr * 64 + lane_k * 4;
  const int col0 = n0 + wc * 64 + lane_r;
  if (OUT_BF16) {
    u16* Co = (u16*)C;
#pragma unroll
    for (int m = 0; m < 4; ++m)
#pragma unroll
      for (int n = 0; n < 4; ++n)
#pragma unroll
        for (int j = 0; j < 4; ++j)
          Co[(size_t)(row0 + m * 16 + j) * ldc + col0 + n * 16] = f2b(acc[m][n][j] * alpha);
  } else {
    float* Co = (float*)C;
#pragma unroll
    for (int m = 0; m < 4; ++m)
#pragma unroll
      for (int n = 0; n < 4; ++n)
#pragma unroll
        for (int j = 0; j < 4; ++j)
          Co[(size_t)(row0 + m * 16 + j) * ldc + col0 + n * 16] = acc[m][n][j] * alpha;
  }
}

// In-place causal row softmax over bf16 [4096][4096]; writes 0 above diagonal.
__global__ __launch_bounds__(256)
void softmax_causal(u16* __restrict__ S) {
  const int i = blockIdx.x;
  const int t = threadIdx.x;
  u16* row = S + (size_t)i * 4096;

  u16x8 r0 = *(const u16x8*)(row + t * 16);
  u16x8 r1 = *(const u16x8*)(row + t * 16 + 8);

  float v[16];
  float mx = -__builtin_inff();
#pragma unroll
  for (int c = 0; c < 16; ++c) {
    int j = t * 16 + c;
    float x = b2f(c < 8 ? r0[c] : r1[c - 8]);
    v[c] = (j <= i) ? x : -__builtin_inff();
    mx = fmaxf(mx, v[c]);
  }
#pragma unroll
  for (int off = 32; off >= 1; off >>= 1) mx = fmaxf(mx, __shfl_xor(mx, off));
  __shared__ float red[8];
  if ((t & 63) == 0) red[t >> 6] = mx;
  __syncthreads();
  mx = fmaxf(fmaxf(red[0], red[1]), fmaxf(red[2], red[3]));

  float s = 0.f;
#pragma unroll
  for (int c = 0; c < 16; ++c) {
    float e = exp2f((v[c] - mx) * 1.4426950408889634f);
    v[c] = e;
    s += e;
  }
#pragma unroll
  for (int off = 32; off >= 1; off >>= 1) s += __shfl_xor(s, off);
  if ((t & 63) == 0) red[4 + (t >> 6)] = s;
  __syncthreads();
  s = red[4] + red[5] + red[6] + red[7];
  float inv = 1.0f / s;

  u16x8 o0, o1;
#pragma unroll
  for (int c = 0; c < 8; ++c) {
    o0[c] = f2b(v[c] * inv);
    o1[c] = f2b(v[c + 8] * inv);
  }
  *(u16x8*)(row + t * 16) = o0;
  *(u16x8*)(row + t * 16 + 8) = o1;
}

extern "C" void kernel_launch(void* const* d_in, const int* in_sizes, int n_in,
                              void* d_out, int out_size, void* d_ws, size_t ws_size,
                              hipStream_t stream) {
  const float* x  = (const float*)d_in[0];
  const float* wq = (const float*)d_in[1];
  const float* wk = (const float*)d_in[2];
  const float* wv = (const float*)d_in[3];

  // workspace layout (bf16 elements); wq/wk/wv contiguous = W [6144][2048]
  u16* x_bf  = (u16*)d_ws;
  u16* wq_bf = x_bf  + (size_t)4096 * 2048;
  u16* wk_bf = wq_bf + (size_t)2048 * 2048;
  u16* wv_bf = wk_bf + (size_t)2048 * 2048;
  u16* K_bf  = wv_bf + (size_t)2048 * 2048;
  u16* VT_bf = K_bf  + (size_t)4096 * 2048;
  u16* S_bf  = VT_bf + (size_t)2048 * 4096;
  u16* Q_bf  = (u16*)d_out;  // Q parked in d_out; dead before PV overwrites

  const float alpha = 0.022097086912079612f;  // 1/sqrt(2048)

  cast_f32_bf16<<<dim3(4096), 256, 0, stream>>>(x,  x_bf,  4096 * 2048);
  cast_f32_bf16<<<dim3(2048), 256, 0, stream>>>(wq, wq_bf, 2048 * 2048);
  cast_f32_bf16<<<dim3(2048), 256, 0, stream>>>(wk, wk_bf, 2048 * 2048);
  cast_f32_bf16<<<dim3(2048), 256, 0, stream>>>(wv, wv_bf, 2048 * 2048);

  // fused [Q|K|V^T] = x . W^T  (256x128 tiles, read-ahead pipeline, 96KB LDS)
  gemm_qkv<<<dim3(48, 16), 512, 98304, stream>>>(x_bf, wq_bf, Q_bf, K_bf, VT_bf);
  // S = alpha * Q . K^T  [4096x4096] bf16, causal block skip
  gemm_bt<true, true, false><<<dim3(32, 32), 256, 0, stream>>>(
      Q_bf, K_bf, S_bf, 2048, 2048, 2048, 4096, alpha);
  // row softmax with causal mask, in place
  softmax_causal<<<dim3(4096), 256, 0, stream>>>(S_bf);
  // O = P . V  [4096x2048] f32, K clamped to (bm+1)*128
  gemm_bt<false, false, true><<<dim3(16, 32), 256, 0, stream>>>(
      S_bf, VT_bf, d_out, 4096, 4096, 4096, 2048, 1.0f);
}

// Round 5
// 249.145 us; speedup vs baseline: 1.5207x; 1.2386x over previous
//
#include <hip/hip_runtime.h>

// SelfAttention: S=4096, EMB=2048, DQ=DV=2048, causal softmax(QK^T/sqrt(DQ))V
// Round 5: port the round-4 read-ahead pipeline to 128x128/4-wave (64KB LDS,
// 2 blocks/CU) for S-GEMM (compact triangular grid) and PV (heavy-first
// K-clamp). QKV keeps the round-4 256x128 kernel. Casts fused to one launch.

using u16 = unsigned short;
typedef __bf16 bf16x8 __attribute__((ext_vector_type(8)));
typedef float  f32x4  __attribute__((ext_vector_type(4)));
typedef u16    u16x8  __attribute__((ext_vector_type(8)));

__device__ __forceinline__ u16 f2b(float f) {
  union { float f; unsigned u; } x; x.f = f;
  unsigned r = x.u + 0x7fffu + ((x.u >> 16) & 1u);  // RNE
  return (u16)(r >> 16);
}
__device__ __forceinline__ float b2f(u16 h) {
  union { unsigned u; float f; } x; x.u = ((unsigned)h) << 16;
  return x.f;
}

#define GLL16(src, dst)                                                        \
  __builtin_amdgcn_global_load_lds(                                            \
      (const __attribute__((address_space(1))) void*)(src),                    \
      (__attribute__((address_space(3))) void*)(dst), 16, 0, 0)

#define MFMA_BF16(a, b, c) __builtin_amdgcn_mfma_f32_16x16x32_bf16(a, b, c, 0, 0, 0)

// One fused cast: regions are block-aligned (2048 elems/block).
// dst is x_bf|wq_bf|wk_bf|wv_bf contiguous.
__global__ __launch_bounds__(256)
void cast_all(const float* __restrict__ x, const float* __restrict__ wq,
              const float* __restrict__ wk, const float* __restrict__ wv,
              u16* __restrict__ dst) {
  const int b = blockIdx.x;  // 10240 blocks
  const float* src;
  size_t off;
  if (b < 4096)      { src = x;  off = (size_t)b * 2048; }
  else if (b < 6144) { src = wq; off = (size_t)(b - 4096) * 2048; }
  else if (b < 8192) { src = wk; off = (size_t)(b - 6144) * 2048; }
  else               { src = wv; off = (size_t)(b - 8192) * 2048; }
  const size_t e = off + (size_t)threadIdx.x * 8;
  float4 a = *(const float4*)(src + e);
  float4 c = *(const float4*)(src + e + 4);
  u16x8 o;
  o[0] = f2b(a.x); o[1] = f2b(a.y); o[2] = f2b(a.z); o[3] = f2b(a.w);
  o[4] = f2b(c.x); o[5] = f2b(c.y); o[6] = f2b(c.z); o[7] = f2b(c.w);
  *(u16x8*)(dst + (size_t)b * 2048 + (size_t)threadIdx.x * 8) = o;
}

// ---------------------------------------------------------------------------
// QKV: [Q|K|V^T] = x(4096x2048) . W^T(6144x2048).  (unchanged from round 4)
// Tile 256x128, BK=64, 8 waves 4Mx2N, grid 768 = 3/CU, 96KB LDS, read-ahead
// pipeline with counted vmcnt(6), T2 swizzle.
// ---------------------------------------------------------------------------
__global__ __launch_bounds__(512)
void gemm_qkv(const u16* __restrict__ A, const u16* __restrict__ W,
              u16* __restrict__ Qo, u16* __restrict__ Ko,
              u16* __restrict__ VTo) {
  extern __shared__ char lds[];
  constexpr int NT = 32;  // 2048/64
  const int bn = blockIdx.x, bm = blockIdx.y;
  const int tid = threadIdx.x;
  const int w = tid >> 6, lane = tid & 63;
  const int wr = w >> 1, wc = w & 1;
  const int l15 = lane & 15, l4 = lane >> 4;
  const int rs = lane >> 3;
  const int csw = ((lane & 7) ^ rs) << 3;
  const int m0 = bm * 256, n0 = bn * 128;

  const u16* gA = A + (size_t)(m0 + w * 8 + rs) * 2048 + csw;
  const u16* gB = W + (size_t)(n0 + w * 8 + rs) * 2048 + csw;
  char* lw = lds + w * 1024;
  const u16* sm = (const u16*)lds;

  auto stA = [&](int p, int u, int tt) {
    GLL16(gA + (size_t)u * 64 * 2048 + tt * 64, lw + p * 49152 + u * 8192);
  };
  auto stB = [&](int p, int u, int tt) {
    GLL16(gB + (size_t)u * 64 * 2048 + tt * 64, lw + p * 49152 + 32768 + u * 8192);
  };
  const int swz = (l15 & 7) << 3;
  auto rdA = [&](int p, int m, int kk) -> bf16x8 {
    int e = p * 24576 + wr * 4096 + (((m * 16 + l15) * 64 + kk * 32 + l4 * 8) ^ swz);
    return *(const bf16x8*)&sm[e];
  };
  auto rdB = [&](int p, int n, int kk) -> bf16x8 {
    int e = p * 24576 + 16384 + wc * 4096 +
            (((n * 16 + l15) * 64 + kk * 32 + l4 * 8) ^ swz);
    return *(const bf16x8*)&sm[e];
  };

  f32x4 acc[4][4] = {};
  bf16x8 aE[4][2], aO[4][2], b01E[2][2], b01O[2][2], b23E[2][2], b23O[2][2];

  stA(0,0,0); stA(0,1,0); stA(0,2,0); stA(0,3,0); stB(0,0,0); stB(0,1,0);
  stA(1,0,1); stA(1,1,1); stA(1,2,1); stA(1,3,1); stB(1,0,1); stB(1,1,1);
  asm volatile("s_waitcnt vmcnt(6)" ::: "memory");
  __builtin_amdgcn_sched_barrier(0);
  __builtin_amdgcn_s_barrier();
#pragma unroll
  for (int m = 0; m < 4; ++m) { aE[m][0] = rdA(0,m,0); aE[m][1] = rdA(0,m,1); }
#pragma unroll
  for (int n = 0; n < 2; ++n) { b01E[n][0] = rdB(0,n,0); b01E[n][1] = rdB(0,n,1); }
  asm volatile("s_waitcnt lgkmcnt(0)" ::: "memory");
  __builtin_amdgcn_sched_barrier(0);
  __builtin_amdgcn_s_barrier();

  for (int i = 0; i < NT / 2; ++i) {
    const int te = 2 * i, to = 2 * i + 1;
    // tile te (buf0) ph0
    if (te + 2 < NT) { stA(0,0,te+2); stA(0,1,te+2); stA(0,2,te+2); }
#pragma unroll
    for (int n = 0; n < 2; ++n) { b23E[n][0] = rdB(0,n+2,0); b23E[n][1] = rdB(0,n+2,1); }
    __builtin_amdgcn_s_barrier();
    __builtin_amdgcn_s_setprio(1);
#pragma unroll
    for (int m = 0; m < 4; ++m)
#pragma unroll
      for (int n = 0; n < 2; ++n)
#pragma unroll
        for (int kk = 0; kk < 2; ++kk)
          acc[m][n] = MFMA_BF16(aE[m][kk], b01E[n][kk], acc[m][n]);
    __builtin_amdgcn_s_setprio(0);
    asm volatile("s_waitcnt lgkmcnt(0)" ::: "memory");
    __builtin_amdgcn_sched_barrier(0);
    __builtin_amdgcn_s_barrier();
    // tile te ph1
    if (te + 2 < NT) {
      stA(0,3,te+2); stB(0,0,te+2); stB(0,1,te+2);
      asm volatile("s_waitcnt vmcnt(6)" ::: "memory");
    } else {
      asm volatile("s_waitcnt vmcnt(0)" ::: "memory");
    }
    __builtin_amdgcn_sched_barrier(0);
    __builtin_amdgcn_s_barrier();
#pragma unroll
    for (int m = 0; m < 4; ++m) { aO[m][0] = rdA(1,m,0); aO[m][1] = rdA(1,m,1); }
#pragma unroll
    for (int n = 0; n < 2; ++n) { b01O[n][0] = rdB(1,n,0); b01O[n][1] = rdB(1,n,1); }
    __builtin_amdgcn_s_setprio(1);
#pragma unroll
    for (int m = 0; m < 4; ++m)
#pragma unroll
      for (int n = 0; n < 2; ++n)
#pragma unroll
        for (int kk = 0; kk < 2; ++kk)
          acc[m][n+2] = MFMA_BF16(aE[m][kk], b23E[n][kk], acc[m][n+2]);
    __builtin_amdgcn_s_setprio(0);
    asm volatile("s_waitcnt lgkmcnt(0)" ::: "memory");
    __builtin_amdgcn_sched_barrier(0);
    __builtin_amdgcn_s_barrier();
    // tile to (buf1) ph0
    if (to + 2 < NT) { stA(1,0,to+2); stA(1,1,to+2); stA(1,2,to+2); }
#pragma unroll
    for (int n = 0; n < 2; ++n) { b23O[n][0] = rdB(1,n+2,0); b23O[n][1] = rdB(1,n+2,1); }
    __builtin_amdgcn_s_barrier();
    __builtin_amdgcn_s_setprio(1);
#pragma unroll
    for (int m = 0; m < 4; ++m)
#pragma unroll
      for (int n = 0; n < 2; ++n)
#pragma unroll
        for (int kk = 0; kk < 2; ++kk)
          acc[m][n] = MFMA_BF16(aO[m][kk], b01O[n][kk], acc[m][n]);
    __builtin_amdgcn_s_setprio(0);
    asm volatile("s_waitcnt lgkmcnt(0)" ::: "memory");
    __builtin_amdgcn_sched_barrier(0);
    __builtin_amdgcn_s_barrier();
    // tile to ph1
    if (to + 2 < NT) {
      stA(1,3,to+2); stB(1,0,to+2); stB(1,1,to+2);
      asm volatile("s_waitcnt vmcnt(6)" ::: "memory");
    } else if (to + 1 < NT) {
      asm volatile("s_waitcnt vmcnt(0)" ::: "memory");
    }
    __builtin_amdgcn_sched_barrier(0);
    __builtin_amdgcn_s_barrier();
    if (to + 1 < NT) {
#pragma unroll
      for (int m = 0; m < 4; ++m) { aE[m][0] = rdA(0,m,0); aE[m][1] = rdA(0,m,1); }
#pragma unroll
      for (int n = 0; n < 2; ++n) { b01E[n][0] = rdB(0,n,0); b01E[n][1] = rdB(0,n,1); }
    }
    __builtin_amdgcn_s_setprio(1);
#pragma unroll
    for (int m = 0; m < 4; ++m)
#pragma unroll
      for (int n = 0; n < 2; ++n)
#pragma unroll
        for (int kk = 0; kk < 2; ++kk)
          acc[m][n+2] = MFMA_BF16(aO[m][kk], b23O[n][kk], acc[m][n+2]);
    __builtin_amdgcn_s_setprio(0);
    asm volatile("s_waitcnt lgkmcnt(0)" ::: "memory");
    __builtin_amdgcn_sched_barrier(0);
    __builtin_amdgcn_s_barrier();
  }

  const int row0 = m0 + wr * 64 + l4 * 4;
  const int cg0 = n0 + wc * 64 + l15;
  if (bn < 16) {
#pragma unroll
    for (int m = 0; m < 4; ++m)
#pragma unroll
      for (int n = 0; n < 4; ++n)
#pragma unroll
        for (int j = 0; j < 4; ++j)
          Qo[(size_t)(row0 + m * 16 + j) * 2048 + cg0 + n * 16] = f2b(acc[m][n][j]);
  } else if (bn < 32) {
#pragma unroll
    for (int m = 0; m < 4; ++m)
#pragma unroll
      for (int n = 0; n < 4; ++n)
#pragma unroll
        for (int j = 0; j < 4; ++j)
          Ko[(size_t)(row0 + m * 16 + j) * 2048 + (cg0 + n * 16 - 2048)] = f2b(acc[m][n][j]);
  } else {
#pragma unroll
    for (int m = 0; m < 4; ++m)
#pragma unroll
      for (int n = 0; n < 4; ++n)
#pragma unroll
        for (int j = 0; j < 4; ++j)
          VTo[(size_t)(cg0 + n * 16 - 4096) * 4096 + row0 + m * 16 + j] = f2b(acc[m][n][j]);
  }
}

// ---------------------------------------------------------------------------
// pipe128: round-4 read-ahead pipeline at 128x128 tile, 4 waves (2Mx2N),
// BK=64, 64KB LDS double-buffered (2 blocks/CU). Stage groups: ph0 = 4x A,
// ph1 = 4x B + vmcnt(8) (one tile = 8 per-wave loads in flight).
// MODE 0: S = alpha * Q . K^T  (bf16 out, compact triangular grid 528)
// MODE 1: O = P . V            (f32 out, K-clamp, heavy-first grid 512)
// ---------------------------------------------------------------------------
template<int MODE>
__global__ __launch_bounds__(256)
void pipe128(const u16* __restrict__ A, const u16* __restrict__ B,
             void* __restrict__ C, float alpha) {
  extern __shared__ char lds[];
  constexpr int LDA = (MODE == 0) ? 2048 : 4096;
  constexpr int LDB = (MODE == 0) ? 2048 : 4096;

  int bm, bn;
  if (MODE == 0) {
    const int b = blockIdx.x;  // 528 causal tiles, bn <= bm
    int r = (int)((sqrtf(8.f * (float)b + 1.f) - 1.f) * 0.5f);
    while ((r + 1) * (r + 2) / 2 <= b) ++r;
    while (r * (r + 1) / 2 > b) --r;
    bm = r; bn = b - r * (r + 1) / 2;
  } else {
    const int b = blockIdx.x;  // 512; heavy rows (large bm) dispatched first
    bm = 31 - (b >> 4); bn = b & 15;
  }
  const int NT = (MODE == 0) ? 32 : 2 * (bm + 1);  // K-tiles of 64 (always even, >=2)

  const int tid = threadIdx.x;
  const int w = tid >> 6, lane = tid & 63;
  const int wr = w >> 1, wc = w & 1;
  const int l15 = lane & 15, l4 = lane >> 4;
  const int rs = lane >> 3;
  const int csw = ((lane & 7) ^ rs) << 3;
  const int m0 = bm * 128, n0 = bn * 128;

  const u16* gA = A + (size_t)(m0 + w * 8 + rs) * LDA + csw;
  const u16* gB = B + (size_t)(n0 + w * 8 + rs) * LDB + csw;
  char* lw = lds + w * 1024;
  const u16* sm = (const u16*)lds;

  auto stA = [&](int p, int u, int tt) {  // A unit u = 32 rows
    GLL16(gA + (size_t)(u * 32) * LDA + tt * 64, lw + p * 32768 + u * 4096);
  };
  auto stB = [&](int p, int u, int tt) {
    GLL16(gB + (size_t)(u * 32) * LDB + tt * 64, lw + p * 32768 + 16384 + u * 4096);
  };
  const int swz = (l15 & 7) << 3;
  auto rdA = [&](int p, int m, int kk) -> bf16x8 {
    int e = p * 16384 + wr * 4096 + (((m * 16 + l15) * 64 + kk * 32 + l4 * 8) ^ swz);
    return *(const bf16x8*)&sm[e];
  };
  auto rdB = [&](int p, int n, int kk) -> bf16x8 {
    int e = p * 16384 + 8192 + wc * 4096 +
            (((n * 16 + l15) * 64 + kk * 32 + l4 * 8) ^ swz);
    return *(const bf16x8*)&sm[e];
  };

  f32x4 acc[4][4] = {};
  bf16x8 aE[4][2], aO[4][2], b01E[2][2], b01O[2][2], b23E[2][2], b23O[2][2];

  // prologue: stage tiles 0 (buf0) and 1 (buf1); allow tile1's 8 outstanding
  stA(0,0,0); stA(0,1,0); stA(0,2,0); stA(0,3,0);
  stB(0,0,0); stB(0,1,0); stB(0,2,0); stB(0,3,0);
  stA(1,0,1); stA(1,1,1); stA(1,2,1); stA(1,3,1);
  stB(1,0,1); stB(1,1,1); stB(1,2,1); stB(1,3,1);
  asm volatile("s_waitcnt vmcnt(8)" ::: "memory");
  __builtin_amdgcn_sched_barrier(0);
  __builtin_amdgcn_s_barrier();
#pragma unroll
  for (int m = 0; m < 4; ++m) { aE[m][0] = rdA(0,m,0); aE[m][1] = rdA(0,m,1); }
#pragma unroll
  for (int n = 0; n < 2; ++n) { b01E[n][0] = rdB(0,n,0); b01E[n][1] = rdB(0,n,1); }
  asm volatile("s_waitcnt lgkmcnt(0)" ::: "memory");
  __builtin_amdgcn_sched_barrier(0);
  __builtin_amdgcn_s_barrier();

  for (int i = 0; i < (NT >> 1); ++i) {
    const int te = 2 * i, to = 2 * i + 1;
    // ---- tile te (buf0) ph0: stage A(te+2) | read b23(te) | MFMA c01 ----
    if (te + 2 < NT) { stA(0,0,te+2); stA(0,1,te+2); stA(0,2,te+2); stA(0,3,te+2); }
#pragma unroll
    for (int n = 0; n < 2; ++n) { b23E[n][0] = rdB(0,n+2,0); b23E[n][1] = rdB(0,n+2,1); }
    __builtin_amdgcn_s_barrier();
    __builtin_amdgcn_s_setprio(1);
#pragma unroll
    for (int m = 0; m < 4; ++m)
#pragma unroll
      for (int n = 0; n < 2; ++n)
#pragma unroll
        for (int kk = 0; kk < 2; ++kk)
          acc[m][n] = MFMA_BF16(aE[m][kk], b01E[n][kk], acc[m][n]);
    __builtin_amdgcn_s_setprio(0);
    asm volatile("s_waitcnt lgkmcnt(0)" ::: "memory");
    __builtin_amdgcn_sched_barrier(0);
    __builtin_amdgcn_s_barrier();
    // ---- tile te ph1: stage B(te+2) | vmcnt(8) | read tile te+1 | MFMA c23 ----
    if (te + 2 < NT) {
      stB(0,0,te+2); stB(0,1,te+2); stB(0,2,te+2); stB(0,3,te+2);
      asm volatile("s_waitcnt vmcnt(8)" ::: "memory");
    } else {
      asm volatile("s_waitcnt vmcnt(0)" ::: "memory");
    }
    __builtin_amdgcn_sched_barrier(0);
    __builtin_amdgcn_s_barrier();
#pragma unroll
    for (int m = 0; m < 4; ++m) { aO[m][0] = rdA(1,m,0); aO[m][1] = rdA(1,m,1); }
#pragma unroll
    for (int n = 0; n < 2; ++n) { b01O[n][0] = rdB(1,n,0); b01O[n][1] = rdB(1,n,1); }
    __builtin_amdgcn_s_setprio(1);
#pragma unroll
    for (int m = 0; m < 4; ++m)
#pragma unroll
      for (int n = 0; n < 2; ++n)
#pragma unroll
        for (int kk = 0; kk < 2; ++kk)
          acc[m][n+2] = MFMA_BF16(aE[m][kk], b23E[n][kk], acc[m][n+2]);
    __builtin_amdgcn_s_setprio(0);
    asm volatile("s_waitcnt lgkmcnt(0)" ::: "memory");
    __builtin_amdgcn_sched_barrier(0);
    __builtin_amdgcn_s_barrier();
    // ---- tile to (buf1) ph0 ----
    if (to + 2 < NT) { stA(1,0,to+2); stA(1,1,to+2); stA(1,2,to+2); stA(1,3,to+2); }
#pragma unroll
    for (int n = 0; n < 2; ++n) { b23O[n][0] = rdB(1,n+2,0); b23O[n][1] = rdB(1,n+2,1); }
    __builtin_amdgcn_s_barrier();
    __builtin_amdgcn_s_setprio(1);
#pragma unroll
    for (int m = 0; m < 4; ++m)
#pragma unroll
      for (int n = 0; n < 2; ++n)
#pragma unroll
        for (int kk = 0; kk < 2; ++kk)
          acc[m][n] = MFMA_BF16(aO[m][kk], b01O[n][kk], acc[m][n]);
    __builtin_amdgcn_s_setprio(0);
    asm volatile("s_waitcnt lgkmcnt(0)" ::: "memory");
    __builtin_amdgcn_sched_barrier(0);
    __builtin_amdgcn_s_barrier();
    // ---- tile to ph1 ----
    if (to + 2 < NT) {
      stB(1,0,to+2); stB(1,1,to+2); stB(1,2,to+2); stB(1,3,to+2);
      asm volatile("s_waitcnt vmcnt(8)" ::: "memory");
    } else if (to + 1 < NT) {
      asm volatile("s_waitcnt vmcnt(0)" ::: "memory");
    }
    __builtin_amdgcn_sched_barrier(0);
    __builtin_amdgcn_s_barrier();
    if (to + 1 < NT) {
#pragma unroll
      for (int m = 0; m < 4; ++m) { aE[m][0] = rdA(0,m,0); aE[m][1] = rdA(0,m,1); }
#pragma unroll
      for (int n = 0; n < 2; ++n) { b01E[n][0] = rdB(0,n,0); b01E[n][1] = rdB(0,n,1); }
    }
    __builtin_amdgcn_s_setprio(1);
#pragma unroll
    for (int m = 0; m < 4; ++m)
#pragma unroll
      for (int n = 0; n < 2; ++n)
#pragma unroll
        for (int kk = 0; kk < 2; ++kk)
          acc[m][n+2] = MFMA_BF16(aO[m][kk], b23O[n][kk], acc[m][n+2]);
    __builtin_amdgcn_s_setprio(0);
    asm volatile("s_waitcnt lgkmcnt(0)" ::: "memory");
    __builtin_amdgcn_sched_barrier(0);
    __builtin_amdgcn_s_barrier();
  }

  // epilogue: C/D layout col=lane&15, row=(lane>>4)*4+reg
  const int row0 = m0 + wr * 64 + l4 * 4;
  const int col0 = n0 + wc * 64 + l15;
  if (MODE == 0) {
    u16* Co = (u16*)C;
#pragma unroll
    for (int m = 0; m < 4; ++m)
#pragma unroll
      for (int n = 0; n < 4; ++n)
#pragma unroll
        for (int j = 0; j < 4; ++j)
          Co[(size_t)(row0 + m * 16 + j) * 4096 + col0 + n * 16] =
              f2b(acc[m][n][j] * alpha);
  } else {
    float* Co = (float*)C;
#pragma unroll
    for (int m = 0; m < 4; ++m)
#pragma unroll
      for (int n = 0; n < 4; ++n)
#pragma unroll
        for (int j = 0; j < 4; ++j)
          Co[(size_t)(row0 + m * 16 + j) * 2048 + col0 + n * 16] = acc[m][n][j];
  }
}

// In-place causal row softmax over bf16 [4096][4096]; writes 0 above diagonal.
__global__ __launch_bounds__(256)
void softmax_causal(u16* __restrict__ S) {
  const int i = blockIdx.x;
  const int t = threadIdx.x;
  u16* row = S + (size_t)i * 4096;

  u16x8 r0 = *(const u16x8*)(row + t * 16);
  u16x8 r1 = *(const u16x8*)(row + t * 16 + 8);

  float v[16];
  float mx = -__builtin_inff();
#pragma unroll
  for (int c = 0; c < 16; ++c) {
    int j = t * 16 + c;
    float x = b2f(c < 8 ? r0[c] : r1[c - 8]);
    v[c] = (j <= i) ? x : -__builtin_inff();
    mx = fmaxf(mx, v[c]);
  }
#pragma unroll
  for (int off = 32; off >= 1; off >>= 1) mx = fmaxf(mx, __shfl_xor(mx, off));
  __shared__ float red[8];
  if ((t & 63) == 0) red[t >> 6] = mx;
  __syncthreads();
  mx = fmaxf(fmaxf(red[0], red[1]), fmaxf(red[2], red[3]));

  float s = 0.f;
#pragma unroll
  for (int c = 0; c < 16; ++c) {
    float e = exp2f((v[c] - mx) * 1.4426950408889634f);
    v[c] = e;
    s += e;
  }
#pragma unroll
  for (int off = 32; off >= 1; off >>= 1) s += __shfl_xor(s, off);
  if ((t & 63) == 0) red[4 + (t >> 6)] = s;
  __syncthreads();
  s = red[4] + red[5] + red[6] + red[7];
  float inv = 1.0f / s;

  u16x8 o0, o1;
#pragma unroll
  for (int c = 0; c < 8; ++c) {
    o0[c] = f2b(v[c] * inv);
    o1[c] = f2b(v[c + 8] * inv);
  }
  *(u16x8*)(row + t * 16) = o0;
  *(u16x8*)(row + t * 16 + 8) = o1;
}

extern "C" void kernel_launch(void* const* d_in, const int* in_sizes, int n_in,
                              void* d_out, int out_size, void* d_ws, size_t ws_size,
                              hipStream_t stream) {
  const float* x  = (const float*)d_in[0];
  const float* wq = (const float*)d_in[1];
  const float* wk = (const float*)d_in[2];
  const float* wv = (const float*)d_in[3];

  // workspace layout (bf16 elements); x|wq|wk|wv contiguous for fused cast
  u16* x_bf  = (u16*)d_ws;
  u16* wq_bf = x_bf  + (size_t)4096 * 2048;
  u16* K_bf  = wq_bf + (size_t)3 * 2048 * 2048;
  u16* VT_bf = K_bf  + (size_t)4096 * 2048;
  u16* S_bf  = VT_bf + (size_t)2048 * 4096;
  u16* Q_bf  = (u16*)d_out;  // Q parked in d_out; dead before PV overwrites

  const float alpha = 0.022097086912079612f;  // 1/sqrt(2048)

  cast_all<<<dim3(10240), 256, 0, stream>>>(x, wq, wk, wv, x_bf);

  // fused [Q|K|V^T] = x . W^T  (256x128 tiles, read-ahead pipeline, 96KB LDS)
  gemm_qkv<<<dim3(48, 16), 512, 98304, stream>>>(x_bf, wq_bf, Q_bf, K_bf, VT_bf);
  // S = alpha * Q . K^T, compact causal grid (528 blocks, 64KB LDS)
  pipe128<0><<<dim3(528), 256, 65536, stream>>>(Q_bf, K_bf, S_bf, alpha);
  // row softmax with causal mask, in place
  softmax_causal<<<dim3(4096), 256, 0, stream>>>(S_bf);
  // O = P . V, K-clamped, heavy rows first (512 blocks)
  pipe128<1><<<dim3(512), 256, 65536, stream>>>(S_bf, VT_bf, d_out, 1.0f);
}